// Round 1
// baseline (1283.230 us; speedup 1.0000x reference)
//
#include <hip/hip_runtime.h>
#include <cstdint>
#include <cstddef>

#define XLD 161   // x row stride = NFEAT + EXTRA + 1

// ============================ CSR build ============================
__global__ void hist_kernel(const int* __restrict__ row, int* __restrict__ cnt, int E) {
    for (int e = blockIdx.x * blockDim.x + threadIdx.x; e < E; e += gridDim.x * blockDim.x)
        atomicAdd(&cnt[row[e]], 1);
}

__global__ __launch_bounds__(1024) void scan_kernel(int* __restrict__ cnt_cursor,
                                                    int* __restrict__ offs, int n) {
    __shared__ int buf[2048];
    __shared__ int carry;
    int t = threadIdx.x;
    if (t == 0) carry = 0;
    __syncthreads();
    for (int base = 0; base < n; base += 1024) {
        int v = (base + t < n) ? cnt_cursor[base + t] : 0;
        buf[t] = v;
        __syncthreads();
        int src = 0;
        for (int o = 1; o < 1024; o <<= 1) {
            int x = buf[src * 1024 + t];
            if (t >= o) x += buf[src * 1024 + t - o];
            buf[(1 - src) * 1024 + t] = x;
            src ^= 1;
            __syncthreads();
        }
        int inc = buf[src * 1024 + t];
        int exc = inc - v + carry;                 // reads old carry (pre-update)
        if (base + t < n) { offs[base + t] = exc; cnt_cursor[base + t] = exc; }
        int tot = buf[src * 1024 + 1023];
        __syncthreads();
        if (t == 0) carry += tot;
        __syncthreads();
    }
    if (t == 0) offs[n] = carry;
}

__global__ void scatter_kernel(const int* __restrict__ row, const int* __restrict__ col,
                               const float* __restrict__ val, int* __restrict__ cursor,
                               int* __restrict__ colA, float* __restrict__ valA, int E) {
    for (int e = blockIdx.x * blockDim.x + threadIdx.x; e < E; e += gridDim.x * blockDim.x) {
        int r = row[e];
        int p = atomicAdd(&cursor[r], 1);
        colA[p] = col[e];
        valA[p] = val[e];
    }
}

// ============================ GEMM (fp32, K-chunked LDS tiles) ============================
// Out[n x C] = H[n x K] @ W[K x C]  (+bias, relu optional)
// H read from A1 for k < split, else A2 at column (k - split).
template <int K, int C>
__global__ __launch_bounds__(256)
void gemm_kernel(const float* __restrict__ A1, int ld1, int split,
                 const float* __restrict__ A2, int ld2,
                 const float* __restrict__ W, const float* __restrict__ bias, int doRelu,
                 float* __restrict__ Out, int n) {
    constexpr int NC = C / 32;              // cols per thread
    __shared__ float Hs[64 * 68];           // Hs[k][r], stride 68 (16B-aligned rows)
    __shared__ float Ws[64 * C];
    int tid  = threadIdx.x;
    int row0 = blockIdx.x * 64;
    int c0   = tid & 31;
    int r0   = (tid >> 5) * 8;
    float acc[8][NC];
#pragma unroll
    for (int j = 0; j < 8; j++)
#pragma unroll
        for (int a = 0; a < NC; a++) acc[j][a] = 0.f;

#pragma unroll
    for (int kb = 0; kb < K; kb += 64) {
        const int kl = (K - kb) < 64 ? (K - kb) : 64;
        __syncthreads();
        // stage W chunk
        for (int i = tid; i < kl * C; i += 256) {
            int k = i / C, c = i - k * C;
            Ws[k * C + c] = W[(size_t)(kb + k) * C + c];
        }
        // stage H chunk (transposed)
        for (int i = tid; i < 64 * kl; i += 256) {
            int r = i / kl, k = i - r * kl;
            int rr = row0 + r;
            float v = 0.f;
            if (rr < n) {
                int kg = kb + k;
                v = (kg < split) ? A1[(size_t)rr * ld1 + kg]
                                 : A2[(size_t)rr * ld2 + (kg - split)];
            }
            Hs[k * 68 + r] = v;
        }
        __syncthreads();
        for (int k = 0; k < kl; k++) {
            float w[NC];
#pragma unroll
            for (int a = 0; a < NC; a++) w[a] = Ws[k * C + c0 + 32 * a];
            const float4 h0 = *(const float4*)&Hs[k * 68 + r0];
            const float4 h1 = *(const float4*)&Hs[k * 68 + r0 + 4];
            float hv[8] = {h0.x, h0.y, h0.z, h0.w, h1.x, h1.y, h1.z, h1.w};
#pragma unroll
            for (int j = 0; j < 8; j++)
#pragma unroll
                for (int a = 0; a < NC; a++) acc[j][a] = fmaf(hv[j], w[a], acc[j][a]);
        }
    }
#pragma unroll
    for (int j = 0; j < 8; j++) {
        int rr = row0 + r0 + j;
        if (rr < n) {
#pragma unroll
            for (int a = 0; a < NC; a++) {
                float o = acc[j][a];
                int cc = c0 + 32 * a;
                if (bias) o += bias[cc];
                if (doRelu) o = fmaxf(o, 0.f);
                Out[(size_t)rr * C + cc] = o;
            }
        }
    }
}

// ============================ Aggregation (CSR SpMM) + bias + relu + BN stats ============================
template <int C, bool DOBN>
__global__ __launch_bounds__(256)
void agg_kernel(const float* __restrict__ S, const int* __restrict__ offs,
                const int* __restrict__ colA, const float* __restrict__ valA,
                const float* __restrict__ cb, const float* __restrict__ bias,
                float* __restrict__ Hout, float* __restrict__ bsum,
                float* __restrict__ bsumsq, int n) {
    constexpr int NA = C / 32;
    int lane = threadIdx.x & 31;
    int grp  = threadIdx.x >> 5;   // 8 groups of 32 lanes
    float psum[NA], psq[NA];
#pragma unroll
    for (int a = 0; a < NA; a++) { psum[a] = 0.f; psq[a] = 0.f; }

    for (int node = blockIdx.x * 8 + grp; node < n; node += gridDim.x * 8) {
        int e0 = offs[node], e1 = offs[node + 1];
        float acc[NA];
#pragma unroll
        for (int a = 0; a < NA; a++) acc[a] = 0.f;
        float vsum = 0.f;
        for (int e = e0; e < e1; e++) {
            int   c = colA[e];
            float v = valA[e];
            const float* srow = S + (size_t)c * C;
#pragma unroll
            for (int a = 0; a < NA; a++) acc[a] = fmaf(v, srow[lane + 32 * a], acc[a]);
            vsum += v;
        }
#pragma unroll
        for (int a = 0; a < NA; a++) {
            int cc = lane + 32 * a;
            float o = acc[a] + cb[cc] * vsum + bias[cc];
            o = fmaxf(o, 0.f);
            Hout[(size_t)node * C + cc] = o;
            if (DOBN) { psum[a] += o; psq[a] += o * o; }
        }
    }
    if (DOBN) {
        __shared__ float red[DOBN ? 8 * C : 1];
#pragma unroll
        for (int a = 0; a < NA; a++) red[grp * C + lane + 32 * a] = psum[a];
        __syncthreads();
        if (threadIdx.x < C) {
            float s = 0.f;
            for (int g = 0; g < 8; g++) s += red[g * C + threadIdx.x];
            atomicAdd(&bsum[threadIdx.x], s);
        }
        __syncthreads();
#pragma unroll
        for (int a = 0; a < NA; a++) red[grp * C + lane + 32 * a] = psq[a];
        __syncthreads();
        if (threadIdx.x < C) {
            float s = 0.f;
            for (int g = 0; g < 8; g++) s += red[g * C + threadIdx.x];
            atomicAdd(&bsumsq[threadIdx.x], s);
        }
    }
}

// ============================ BN fold: Wf = inv*W, cb = -sum(mean*inv*W) ============================
template <int C>
__global__ __launch_bounds__(256)
void fold_kernel(const float* __restrict__ W, float* __restrict__ bsum,
                 float* __restrict__ bsumsq, float* __restrict__ Wf,
                 float* __restrict__ cb, int N) {
    __shared__ float mean[96], inv[96];
    int t = threadIdx.x;
    float rn = 1.0f / (float)N;
    if (t < 96) {
        float mu  = bsum[t] * rn;
        float var = bsumsq[t] * rn - mu * mu;
        mean[t] = mu;
        inv[t]  = rsqrtf(var + 1e-5f);
        bsum[t] = 0.f;        // re-zero for this layer's agg accumulation
        bsumsq[t] = 0.f;
    }
    __syncthreads();
    for (int i = t; i < 96 * C; i += 256) {
        int k = i / C;
        Wf[i] = inv[k] * W[i];
    }
    if (t < C) {
        float s = 0.f;
        for (int k = 0; k < 96; k++) s += mean[k] * inv[k] * W[k * C + t];
        cb[t] = -s;
    }
}

// ============================ final dot (64->1) + global min ============================
__global__ __launch_bounds__(256)
void dot_min_kernel(const float* __restrict__ A, const float* __restrict__ M3w,
                    const float* __restrict__ M3b, float* __restrict__ m,
                    unsigned* __restrict__ gmin, int n) {
    int lane = threadIdx.x & 63;
    int wv   = threadIdx.x >> 6;
    float w  = M3w[lane];
    float b  = M3b[0];
    float lmin = 3.4e38f;
    int nw = gridDim.x * 4;
    for (int r = blockIdx.x * 4 + wv; r < n; r += nw) {
        float v = A[(size_t)r * 64 + lane] * w;
#pragma unroll
        for (int o = 32; o; o >>= 1) v += __shfl_down(v, o);
        if (lane == 0) {
            float mv = v + b;
            m[r] = mv;
            lmin = fminf(lmin, mv);
        }
    }
#pragma unroll
    for (int o = 32; o; o >>= 1) lmin = fminf(lmin, __shfl_down(lmin, o));
    __shared__ float sm[4];
    if (lane == 0) sm[wv] = lmin;
    __syncthreads();
    if (threadIdx.x == 0) {
        float mn = fminf(fminf(sm[0], sm[1]), fminf(sm[2], sm[3]));
        unsigned u = __float_as_uint(mn);
        unsigned key = (u >> 31) ? ~u : (u | 0x80000000u);
        atomicMin(gmin, key);
    }
}

__global__ void where_kernel(const float* __restrict__ x, float* __restrict__ m,
                             const unsigned* __restrict__ gmin, int n) {
    int i = blockIdx.x * blockDim.x + threadIdx.x;
    if (i < n) {
        unsigned k = *gmin;
        unsigned u = (k >> 31) ? (k ^ 0x80000000u) : ~k;
        float g = __uint_as_float(u);
        if (x[(size_t)i * XLD + 160] == 0.0f) m[i] = g;
    }
}

// ============================ exact radix select: (kwant)-th largest ============================
__device__ inline unsigned fkey(float f) {
    unsigned u = __float_as_uint(f);
    return (u >> 31) ? ~u : (u | 0x80000000u);
}

__global__ __launch_bounds__(1024)
void select_kernel(const float* __restrict__ m, int n, int kwant, float* __restrict__ thresh) {
    __shared__ unsigned hist[256];
    __shared__ unsigned sprefix;
    __shared__ int skk;
    int t = threadIdx.x;
    if (t == 0) { sprefix = 0u; skk = kwant; }
    for (int pass = 0; pass < 4; ++pass) {
        if (t < 256) hist[t] = 0u;
        __syncthreads();
        int shift = 24 - 8 * pass;
        unsigned pfx = sprefix;
        for (int i = t; i < n; i += 1024) {
            unsigned key = fkey(m[i]);
            bool ok = (pass == 0) || ((key >> (shift + 8)) == (pfx >> (shift + 8)));
            if (ok) atomicAdd(&hist[(key >> shift) & 255u], 1u);
        }
        __syncthreads();
        if (t == 0) {
            int cum = 0, kk = skk, chosen = 0;
            for (int b = 255; b >= 0; b--) {
                cum += (int)hist[b];
                if (cum >= kk) { chosen = b; kk -= (cum - (int)hist[b]); break; }
            }
            sprefix = pfx | ((unsigned)chosen << shift);
            skk = kk;
        }
        __syncthreads();
    }
    if (t == 0) {
        unsigned key = sprefix;
        unsigned u = (key >> 31) ? (key ^ 0x80000000u) : ~key;
        *thresh = __uint_as_float(u);
    }
}

__global__ void mask_kernel(const float* __restrict__ m, const float* __restrict__ thresh,
                            float* __restrict__ out, int n) {
    int i = blockIdx.x * blockDim.x + threadIdx.x;
    if (i < n) {
        float t = *thresh, v = m[i];
        out[i] = (v > t) ? v * (1.0f / v) : 0.0f;
    }
}

// ============================ launch ============================
extern "C" void kernel_launch(void* const* d_in, const int* in_sizes, int n_in,
                              void* d_out, int out_size, void* d_ws, size_t ws_size,
                              hipStream_t stream) {
    const float* x   = (const float*)d_in[0];
    const int*   row = (const int*)d_in[1];
    const int*   col = (const int*)d_in[2];
    const float* val = (const float*)d_in[3];
    const float* W1  = (const float*)d_in[4];
    const float* b1  = (const float*)d_in[5];
    const float* W2  = (const float*)d_in[6];
    const float* b2  = (const float*)d_in[7];
    const float* W3  = (const float*)d_in[8];
    const float* b3  = (const float*)d_in[9];
    const float* W4  = (const float*)d_in[10];
    const float* b4  = (const float*)d_in[11];
    const float* W5  = (const float*)d_in[12];
    const float* b5  = (const float*)d_in[13];
    const float* M1w = (const float*)d_in[14];
    const float* M1b = (const float*)d_in[15];
    const float* M2w = (const float*)d_in[16];
    const float* M2b = (const float*)d_in[17];
    const float* M3w = (const float*)d_in[18];
    const float* M3b = (const float*)d_in[19];

    const int n = in_sizes[0] / XLD;   // 50000
    const int E = in_sizes[1];         // 800000

    char* ws = (char*)d_ws;
    size_t off = 0;
    auto carve = [&](size_t bytes) -> void* {
        void* p = ws + off;
        off = (off + bytes + 255) & ~(size_t)255;
        return p;
    };
    int*      offs   = (int*)carve((size_t)(n + 1) * 4);
    int*      cursor = (int*)carve((size_t)n * 4);        // also the histogram buffer
    int*      colA   = (int*)carve((size_t)E * 4);
    float*    valA   = (float*)carve((size_t)E * 4);
    float*    h      = (float*)carve((size_t)n * 96 * 4); // layer activations (h5 = first n*64)
    float*    big    = (float*)carve((size_t)n * 128 * 4);// s buffer (n*96) / a1 (n*128)
    float*    Wf     = (float*)carve(96 * 96 * 4);
    float*    stats  = (float*)carve(288 * 4);            // cb0 | bsum | bsumsq
    float*    cb     = (float*)carve(96 * 4);
    float*    m      = (float*)carve((size_t)n * 4);
    unsigned* gmin   = (unsigned*)carve(4);
    float*    thresh = (float*)carve(4);
    float* cb0    = stats;
    float* bsum   = stats + 96;
    float* bsumsq = stats + 192;

    hipMemsetAsync(cursor, 0, (size_t)n * 4, stream);
    hipMemsetAsync(stats, 0, 288 * 4, stream);
    hipMemsetAsync(gmin, 0xFF, 4, stream);

    // CSR build
    hist_kernel<<<512, 256, 0, stream>>>(row, cursor, E);
    scan_kernel<<<1, 1024, 0, stream>>>(cursor, offs, n);
    scatter_kernel<<<512, 256, 0, stream>>>(row, col, val, cursor, colA, valA, E);

    const int gg = (n + 63) / 64;

    // Layer 1: s = x[:, :128] @ W1 ; agg + b1 + relu ; accumulate BN stats
    gemm_kernel<128, 96><<<gg, 256, 0, stream>>>(x, XLD, 128, x, XLD, W1, nullptr, 0, big, n);
    agg_kernel<96, true><<<1024, 256, 0, stream>>>(big, offs, colA, valA, cb0, b1, h, bsum, bsumsq, n);

    // Layers 2-4: fold BN into W, gemm, agg (+BN stats)
    fold_kernel<96><<<1, 256, 0, stream>>>(W2, bsum, bsumsq, Wf, cb, n);
    gemm_kernel<96, 96><<<gg, 256, 0, stream>>>(h, 96, 96, h, 96, Wf, nullptr, 0, big, n);
    agg_kernel<96, true><<<1024, 256, 0, stream>>>(big, offs, colA, valA, cb, b2, h, bsum, bsumsq, n);

    fold_kernel<96><<<1, 256, 0, stream>>>(W3, bsum, bsumsq, Wf, cb, n);
    gemm_kernel<96, 96><<<gg, 256, 0, stream>>>(h, 96, 96, h, 96, Wf, nullptr, 0, big, n);
    agg_kernel<96, true><<<1024, 256, 0, stream>>>(big, offs, colA, valA, cb, b3, h, bsum, bsumsq, n);

    fold_kernel<96><<<1, 256, 0, stream>>>(W4, bsum, bsumsq, Wf, cb, n);
    gemm_kernel<96, 96><<<gg, 256, 0, stream>>>(h, 96, 96, h, 96, Wf, nullptr, 0, big, n);
    agg_kernel<96, true><<<1024, 256, 0, stream>>>(big, offs, colA, valA, cb, b4, h, bsum, bsumsq, n);

    // Layer 5: fold BN of h4 into W5, gemm (96->64), agg + b5 + relu (no BN)
    fold_kernel<64><<<1, 256, 0, stream>>>(W5, bsum, bsumsq, Wf, cb, n);
    gemm_kernel<96, 64><<<gg, 256, 0, stream>>>(h, 96, 96, h, 96, Wf, nullptr, 0, big, n);
    agg_kernel<64, false><<<1024, 256, 0, stream>>>(big, offs, colA, valA, cb, b5, h, bsum, bsumsq, n);

    // MLP: a1 = relu([h5 | x[:,128:160]] @ M1w + M1b) ; a2 = relu(a1 @ M2w + M2b)
    gemm_kernel<96, 128><<<gg, 256, 0, stream>>>(h, 64, 64, x + 128, XLD, M1w, M1b, 1, big, n);
    gemm_kernel<128, 64><<<gg, 256, 0, stream>>>(big, 128, 128, big, 128, M2w, M2b, 1, h, n);

    // m = a2 @ M3w + M3b ; global min
    dot_min_kernel<<<256, 256, 0, stream>>>(h, M3w, M3b, m, gmin, n);

    // where(grp==0, min, m)
    where_kernel<<<(n + 255) / 256, 256, 0, stream>>>(x, m, gmin, n);

    // exact 71st-largest threshold
    select_kernel<<<1, 1024, 0, stream>>>(m, n, 71, thresh);

    // out = m>thresh ? m*(1/m) : 0
    mask_kernel<<<(n + 255) / 256, 256, 0, stream>>>(m, thresh, (float*)d_out, n);
}